// Round 12
// baseline (3484.057 us; speedup 1.0000x reference)
//
#include <hip/hip_runtime.h>
#include <math.h>

typedef _Float16 f16;
typedef __attribute__((ext_vector_type(8))) _Float16 half8;
typedef __attribute__((ext_vector_type(4))) float f32x4;

template <int N> struct ic { static constexpr int v = N; };

static __device__ __forceinline__ float sigmoid_f(float x) { return 1.0f / (1.0f + expf(-x)); }

// exact split: x == (float)hi + (float)lo / 4096 (lo pre-scaled to dodge denormals)
static __device__ __forceinline__ void splitf(float x, f16& hi, f16& lo) {
    hi = (f16)x;
    float r = x - (float)hi;
    lo = (f16)(r * 4096.0f);
}

// vmcnt-only s_waitcnt immediate (gfx9): vm[3:0] | exp[6:4]=7 | lgkm[11:8]=15 | vm[5:4]@[15:14]
constexpr unsigned vmcnt_enc(int n) {
    return (unsigned)((n & 15) | (7 << 4) | (15 << 8) | ((n >> 4) << 14));
}
// vmcnt(n) AND lgkmcnt(0) in one wait
constexpr unsigned vm_lgkm0_enc(int n) {
    return (unsigned)((n & 15) | (7 << 4) | (0 << 8) | ((n >> 4) << 14));
}

// async global->LDS, 16B per lane: LDS dest = uniform base + lane*16, global src per-lane.
static __device__ __forceinline__ void lds_stage16(const f16* src, f16* dst) {
    typedef const __attribute__((address_space(1))) unsigned int* gup;
    typedef __attribute__((address_space(3))) unsigned int* lup;
    __builtin_amdgcn_global_load_lds((gup)(const void*)src, (lup)(void*)dst, 16, 0, 0);
}

// ---------------------------------------------------------------------------
// Tap-decomposed implicit-GEMM conv, f16 MFMA, 2-term activation split,
// fp32 accumulate.
// R12 = R11 resubmitted verbatim (R11 bench died to container-infra failure;
// audit found no hang mechanism: barriers wave-uniform, waits terminate,
// ring algebra + vmcnt counts verified).
// R11: EARLY-BARRIER schedule.  R10 measured MfmaUtil 35% with ~150cyc of
// exposed LDS latency per group top (post-barrier BAH-prefix ds_reads gate
// the first MFMA).  Restructure: the barrier moves to after step STG-2's
// MFMA -- lgkmcnt(0) drains this group's ds_reads, vmcnt((STG-1)*NG*2)
// certifies stage(g+1) (exactly that many vm-ops issued after the stage
// pieces).  The LAST step then cross-preloads the next group's step-0
// B-frags from the certified buffer, so groups chain with NO top barrier
// and operands already in registers.  Safety ledger: all cur-reads issue
// pre-barrier + drained; stage(g+2) (overwrites cur) issues only after all
// waves pass the barrier; BAH==1 makes the cross-read provably post-barrier;
// STG%NB==0 keeps ring indexing continuous.  R9 race fix retained
// (sched_barrier pins [stage][A-loads] issue order).
// Ledger: R5 narrow / R9-R10 wide (both directions); R6 BAH-deep regression;
// R4 per-step fencing regression; R8 race -> R9 fix verified by R10 g3zr.
//   A-frag: lane&15=pixel, k=(lane>>4)*8+j ; B-frag: lane&15=oc, same k.
//   D-frag: col(oc)=lane&15, row(pixel)=(lane>>4)*4+reg  [HW-verified]
// ---------------------------------------------------------------------------
template <int KH, int KW, int KPT, int MODE, int NG, int NOC, int D, int STG, int BAH,
          int CBI, int KB0, int WPI, int PIXPI,
          int WSH, int HWOUT, int OC, int STRIDE, int POFF,
          int CBO, int OCH0, int WPO, int PIXPO>
static __device__ __forceinline__ void gemm_conv_body(
    int bx, int by, int b,
    const f16* Ah, const f16* Al, const f16* __restrict__ Wt,
    const float* __restrict__ bias, const float* __restrict__ zbuf,
    float* zout, f16* Oh, f16* Ol, f16* smem)
{
    constexpr int NSTEP = KH * KW * KPT;
    constexpr int WOUT  = 1 << WSH;
    constexpr int OCB   = OC / 16;
    constexpr int NGRP  = NSTEP / STG;
    constexpr int U     = (D > STG) ? (D / STG) : 1;   // phase-unroll factor
    constexpr int NB    = BAH + 1;                     // B ring depth
    constexpr int PPW   = (STG * NOC) / 4;             // staged 1KB pieces per wave
    static_assert(NSTEP % STG == 0, "NSTEP % STG");
    static_assert(NSTEP % D == 0, "NSTEP % D");
    static_assert(U == 1 ? (STG % D == 0) : (D % STG == 0 && NGRP % U == 0), "phase");
    static_assert(U <= 2, "U support");
    static_assert(BAH == 1, "early-barrier scheme requires BAH==1");
    static_assert(STG % NB == 0, "ring continuity across groups");
    static_assert(STG >= 2, "early barrier needs >=2 steps");
    static_assert(STG * NOC * 512 <= 8192, "group fits buffer");

    const int lane = threadIdx.x & 63;
    const int wave = threadIdx.x >> 6;
    const int pixbase = (bx * 4 + wave) * (NG * 16);
    const int ocbase  = by * (NOC * 16);

    const f16* ph[NG];
    const f16* pl[NG];
#pragma unroll
    for (int g = 0; g < NG; ++g) {
        int apix = pixbase + 16 * g + (lane & 15);
        int y = apix >> WSH, x = apix & (WOUT - 1);
        int p0 = (y * STRIDE + POFF) * WPI + (x * STRIDE + POFF);
        size_t o = ((size_t)(b * CBI + KB0) * PIXPI + p0) * 32 + (lane >> 4) * 8;
        ph[g] = Ah + o;
        pl[g] = Al + o;
    }

    int lk = 0, lkx = 0;
    auto advance = [&]() {
#pragma unroll
        for (int g = 0; g < NG; ++g) { ph[g] += (size_t)PIXPI * 32; pl[g] += (size_t)PIXPI * 32; }
        if (++lk == KPT) {
            lk = 0;
            int shift = 1;
            if (++lkx == KW) { lkx = 0; shift = WPI - (KW - 1); }
            const long ad = (long)shift * 32 - (long)KPT * PIXPI * 32;
#pragma unroll
            for (int g = 0; g < NG; ++g) { ph[g] += ad; pl[g] += ad; }
        }
    };

    // B piece (1KB = 512 f16 = [kgrp4][oc16][ch8]) for flat step s, oc-block j
    auto bpiece = [&](int s, int j) -> const f16* {
        int t = s / KPT, kb = s % KPT;
        return Wt + (((size_t)(t * OCB + by * NOC + j)) * KPT + kb) * 512;
    };

    auto stage_lds = [&](int g0, f16* dst) {
#pragma unroll
        for (int p = 0; p < PPW; ++p) {
            const int pc = wave * PPW + p;
            const int kk = pc / NOC, j = pc % NOC;
            lds_stage16(bpiece(g0 * STG + kk, j) + lane * 8, dst + pc * 512);
        }
    };

    half8 bh[D][NG], bl[D][NG];
    half8 bwreg[NB][NOC];
    f32x4 acc[NG][NOC] = {};
    f32x4 acc2[NG][NOC] = {};

    // prologue: stage group 0 (issue-order pinned); fill A pipeline D-1 deep;
    // certify stage via counted vmcnt; preload group 0's step-0 B frags.
    stage_lds(0, smem);
    __builtin_amdgcn_sched_barrier(0);
#pragma unroll
    for (int s = 0; s < D - 1; ++s) {
#pragma unroll
        for (int g = 0; g < NG; ++g) {
            bh[s][g] = *(const half8*)ph[g];
            bl[s][g] = *(const half8*)pl[g];
        }
        advance();
    }
    __builtin_amdgcn_s_waitcnt(vmcnt_enc((D - 1) * NG * 2));
    asm volatile("" ::: "memory");
    __builtin_amdgcn_s_barrier();
    __builtin_amdgcn_sched_barrier(0);
#pragma unroll
    for (int q = 0; q < BAH; ++q)
#pragma unroll
        for (int j = 0; j < NOC; ++j)
            bwreg[q % NB][j] = *(const half8*)(smem + (q * NOC + j) * 512 + lane * 8);

    auto group_body = [&](auto phc, int gi) __attribute__((always_inline)) {
        constexpr int PH = decltype(phc)::v;
        constexpr int PB = PH * STG;                 // flat-step phase base
        const int par = (U == 2) ? PH : (gi & 1);
        f16* cur = smem + par * 8192;
        f16* nxt = smem + (par ^ 1) * 8192;
        const bool has_next = (gi + 1 < NGRP);
        if (has_next) {
            stage_lds(gi + 1, nxt);                  // async into other buffer
            __builtin_amdgcn_sched_barrier(0);       // pin: stage issues before group's A-loads
        }
#pragma unroll
        for (int kk = 0; kk < STG; ++kk) {
            if (kk + BAH < STG) {
#pragma unroll
                for (int j = 0; j < NOC; ++j)
                    bwreg[(PB + kk + BAH) % NB][j] =
                        *(const half8*)(cur + ((kk + BAH) * NOC + j) * 512 + lane * 8);
            } else if (has_next) {
                // cross-boundary preload of next group's step 0 (BAH==1 -> only
                // at kk==STG-1, strictly AFTER the early barrier below).
#pragma unroll
                for (int j = 0; j < NOC; ++j)
                    bwreg[(PB + kk + BAH) % NB][j] =
                        *(const half8*)(nxt + ((kk + BAH - STG) * NOC + j) * 512 + lane * 8);
            }
            const int ls = (PB + kk + D - 1) % D;    // compile-time after unroll
#pragma unroll
            for (int g = 0; g < NG; ++g) {
                bh[ls][g] = *(const half8*)ph[g];
                bl[ls][g] = *(const half8*)pl[g];
            }
            advance();
            const int dd = (PB + kk) % D;
            __builtin_amdgcn_s_setprio(1);
#pragma unroll
            for (int j = 0; j < NOC; ++j)
#pragma unroll
                for (int g = 0; g < NG; ++g) {
                    acc[g][j]  = __builtin_amdgcn_mfma_f32_16x16x32_f16(bh[dd][g], bwreg[(PB + kk) % NB][j], acc[g][j], 0, 0, 0);
                    acc2[g][j] = __builtin_amdgcn_mfma_f32_16x16x32_f16(bl[dd][g], bwreg[(PB + kk) % NB][j], acc2[g][j], 0, 0, 0);
                }
            __builtin_amdgcn_s_setprio(0);
            if (kk == STG - 2 && has_next) {
                // EARLY BARRIER: all of this group's ds_reads are issued -- drain
                // them (lgkm 0); vmcnt((STG-1)*NG*2) = vm-ops issued after the
                // stage pieces -> stage(g+1) certified complete.  After this,
                // no wave touches cur again, and nxt is safe to read.
                __builtin_amdgcn_s_waitcnt(vm_lgkm0_enc((STG - 1) * NG * 2));
                asm volatile("" ::: "memory");
                __builtin_amdgcn_s_barrier();
                __builtin_amdgcn_sched_barrier(0);
            }
        }
    };

#pragma unroll 1
    for (int gi0 = 0; gi0 < NGRP; gi0 += U) {
        group_body(ic<0>{}, gi0);
        if constexpr (U == 2) group_body(ic<1>{}, gi0 + 1);
    }

    constexpr int Cc = (MODE == 0) ? (OC >> 1) : OC;
#pragma unroll
    for (int g = 0; g < NG; ++g) {
#pragma unroll
        for (int j = 0; j < NOC; ++j) {
            const int oc = ocbase + j * 16 + (lane & 15);
            const float bv = bias[oc];
#pragma unroll
            for (int r = 0; r < 4; ++r) {
                const int pix = pixbase + 16 * g + ((lane >> 4) << 2) + r;
                const int y = pix >> WSH, x = pix & (WOUT - 1);
                const int pr = (y + 2) * WPI + (x + 2);
                const int pwr = (y + 2) * WPO + (x + 2);
                const size_t pz = (size_t)b * HWOUT + pix;
                float a = acc[g][j][r] + acc2[g][j][r] * (1.0f / 4096.0f) + bv;
                if (MODE == 0) {
                    float s = sigmoid_f(a);
                    if (oc < Cc) {
                        zout[pz * Cc + oc] = s;
                    } else {
                        int hch = oc - Cc;
                        size_t hidx = ((size_t)(b * CBI + (hch >> 5)) * PIXPI + pr) * 32 + (hch & 31);
                        float hv = (float)Ah[hidx] + (float)Al[hidx] * (1.0f / 4096.0f);
                        float rh = s * hv;
                        f16 hi, lo; splitf(rh, hi, lo);
                        int wch = Cc + oc;  // = 2C + (oc-C)
                        size_t widx = ((size_t)(b * CBO + (wch >> 5)) * PIXPO + pwr) * 32 + (wch & 31);
                        Oh[widx] = hi; Ol[widx] = lo;
                    }
                } else if (MODE == 1) {
                    size_t hidx = ((size_t)(b * CBI + (oc >> 5)) * PIXPI + pr) * 32 + (oc & 31);
                    float hv = (float)Ah[hidx] + (float)Al[hidx] * (1.0f / 4096.0f);
                    float zv = zbuf[pz * Cc + oc];
                    float hn = (1.f - zv) * hv + zv * tanhf(a);
                    f16 hi, lo; splitf(hn, hi, lo);
                    Oh[hidx] = hi; Ol[hidx] = lo;
                } else {
                    f16 hi, lo; splitf(a, hi, lo);
                    int wch = OCH0 + oc;
                    size_t widx = ((size_t)(b * CBO + (wch >> 5)) * PIXPO + pwr) * 32 + (wch & 31);
                    Oh[widx] = hi; Ol[widx] = lo;
                }
            }
        }
    }
}

// ---------------------------------------------------------------------------
// conv1 body: IC=1, k4 s2 p1, 128x128 -> 64x64, OC=64, fp32 direct; writes f16
// hi/lo into blocked cat1 xt region (ch [64,128), cblk 2..3, halo 2).
// ---------------------------------------------------------------------------
static __device__ __forceinline__ void conv1_body(
    int bx, int b,
    const float* __restrict__ in, const float* __restrict__ w,
    const float* __restrict__ bias, f16* Oh, f16* Ol)
{
    const int tid = threadIdx.x;
    const int px  = bx * 64 + (tid & 63);
    const int ocg = tid >> 6;
    const int y = px >> 6, x = px & 63;
    const float* src = in + (size_t)b * 196608;
    float v[16];
#pragma unroll
    for (int ky = 0; ky < 4; ++ky)
#pragma unroll
        for (int kx = 0; kx < 4; ++kx) {
            int iy = 2 * y - 1 + ky, ix = 2 * x - 1 + kx;
            v[ky * 4 + kx] = ((unsigned)iy < 128u && (unsigned)ix < 128u) ? src[iy * 128 + ix] : 0.f;
        }
    const int p = (y + 2) * 68 + (x + 2);
#pragma unroll
    for (int o = 0; o < 16; ++o) {
        int ch = 64 + ocg * 16 + o;
        float s = bias[ch - 64];
        const float* wr = w + (ch - 64) * 16;
#pragma unroll
        for (int t = 0; t < 16; ++t) s += wr[t] * v[t];
        f16 hi, lo; splitf(s, hi, lo);
        size_t idx = ((size_t)(b * 6 + (ch >> 5)) * 4624 + p) * 32 + (ch & 31);
        Oh[idx] = hi; Ol[idx] = lo;
    }
}

// ---------------------------------------------------------------------------
// Horizontally-fused pipeline phases.  GRU wavefront: stage1@t, stage2@t-1,
// stage3@t-2 are independent -> fuse each sub-phase across stages.
// LPT ordering: longest-per-block branch gets the LOWEST block IDs.
// ---------------------------------------------------------------------------

// L1: c3(t-2) NOC=4 [0,64) | c2(t-1) NOC=8 [64,192) | conv1(t) [192,704)
__global__ __launch_bounds__(256) void fused_L1(
    const float* __restrict__ input, const float* __restrict__ c1w, const float* __restrict__ c1b,
    f16* cat1h, f16* cat1l,
    const f16* __restrict__ wt_c2, const float* __restrict__ c2b, f16* cat2h, f16* cat2l,
    const f16* __restrict__ wt_c3, const float* __restrict__ c3b, f16* cat3h, f16* cat3l,
    int t1, int a2, int a3)
{
    __shared__ f16 smem[2 * 8192];
    const int lin = blockIdx.x;
    if (lin < 64) {
        if (!a3) return;
        gemm_conv_body<4, 4, 4, 2, 1, 4, 8, 4, 1, 12, 0, 36, 1296, 4, 256, 128, 2, 1, 12, 128, 20, 400>(
            lin & 3, (lin >> 2) & 1, lin >> 3,
            cat2h, cat2l, wt_c3, c3b, nullptr, nullptr, cat3h, cat3l, smem);
    } else if (lin < 192) {
        if (!a2) return;
        const int l = lin - 64;
        gemm_conv_body<4, 4, 2, 2, 1, 8, 4, 2, 1, 6, 0, 68, 4624, 5, 1024, 128, 2, 1, 12, 128, 36, 1296>(
            l & 15, 0, l >> 4,
            cat1h, cat1l, wt_c2, c2b, nullptr, nullptr, cat2h, cat2l, smem);
    } else {
        if (t1 < 0) return;
        const int l = lin - 192;
        conv1_body(l & 63, l >> 6, input + (size_t)t1 * 16384, c1w, c1b, cat1h, cat1l);
    }
}

// L2: g2zr(t-1) NOC=8 [0,256) | g3zr(t-2) NOC=4 [256,384) | g1zr(t) NOC=8 [384,896)
__global__ __launch_bounds__(256) void fused_L2(
    f16* cat1h, f16* cat1l, const f16* __restrict__ wt_g1zr, const float* __restrict__ g1zrb, float* z1,
    f16* cat2h, f16* cat2l, const f16* __restrict__ wt_g2zr, const float* __restrict__ g2zrb, float* z2,
    f16* cat3h, f16* cat3l, const f16* __restrict__ wt_g3zr, const float* __restrict__ g3zrb, float* z3,
    int a1, int a2, int a3)
{
    __shared__ f16 smem[2 * 8192];
    const int lin = blockIdx.x;
    if (lin < 256) {
        if (!a2) return;
        gemm_conv_body<5, 5, 8, 0, 1, 8, 4, 2, 1, 12, 0, 36, 1296, 5, 1024, 256, 1, 0, 12, 0, 36, 1296>(
            lin & 15, (lin >> 4) & 1, lin >> 5,
            cat2h, cat2l, wt_g2zr, g2zrb, nullptr, z2, cat2h, cat2l, smem);
    } else if (lin < 384) {
        if (!a3) return;
        const int l = lin - 256;
        gemm_conv_body<5, 5, 8, 0, 1, 4, 8, 4, 1, 12, 0, 20, 400, 4, 256, 256, 1, 0, 12, 0, 20, 400>(
            l & 3, (l >> 2) & 3, l >> 4,
            cat3h, cat3l, wt_g3zr, g3zrb, nullptr, z3, cat3h, cat3l, smem);
    } else {
        if (!a1) return;
        const int l = lin - 384;
        gemm_conv_body<5, 5, 4, 0, 1, 8, 4, 2, 1, 6, 0, 68, 4624, 6, 4096, 128, 1, 0, 6, 0, 68, 4624>(
            l & 63, 0, l >> 6,
            cat1h, cat1l, wt_g1zr, g1zrb, nullptr, z1, cat1h, cat1l, smem);
    }
}

// L3: g2h(t-1) NOC=8 [0,128) | g3h(t-2) NOC=4 [128,192) | g1h(t) NOC=4 [192,704)
__global__ __launch_bounds__(256) void fused_L3(
    f16* cat1h, f16* cat1l, const f16* __restrict__ wt_g1h, const float* __restrict__ g1hb, const float* z1,
    f16* cat2h, f16* cat2l, const f16* __restrict__ wt_g2h, const float* __restrict__ g2hb, const float* z2,
    f16* cat3h, f16* cat3l, const f16* __restrict__ wt_g3h, const float* __restrict__ g3hb, const float* z3,
    int a1, int a2, int a3)
{
    __shared__ f16 smem[2 * 8192];
    const int lin = blockIdx.x;
    if (lin < 128) {
        if (!a2) return;
        gemm_conv_body<5, 5, 8, 1, 1, 8, 4, 2, 1, 12, 4, 36, 1296, 5, 1024, 128, 1, 0, 12, 0, 36, 1296>(
            lin & 15, 0, lin >> 4,
            cat2h, cat2l, wt_g2h, g2hb, z2, nullptr, cat2h, cat2l, smem);
    } else if (lin < 192) {
        if (!a3) return;
        const int l = lin - 128;
        gemm_conv_body<5, 5, 8, 1, 1, 4, 8, 4, 1, 12, 4, 20, 400, 4, 256, 128, 1, 0, 12, 0, 20, 400>(
            l & 3, (l >> 2) & 1, l >> 3,
            cat3h, cat3l, wt_g3h, g3hb, z3, nullptr, cat3h, cat3l, smem);
    } else {
        if (!a1) return;
        const int l = lin - 192;
        gemm_conv_body<5, 5, 4, 1, 1, 4, 4, 4, 1, 6, 2, 68, 4624, 6, 4096, 64, 1, 0, 6, 0, 68, 4624>(
            l & 63, 0, l >> 6,
            cat1h, cat1l, wt_g1h, g1hb, z1, nullptr, cat1h, cat1l, smem);
    }
}

// w[oc][ic][kh][kw] fp32 -> blocked f16 [tap][ocblk][kblk][kgrp4][oc16][ch8].
// perm=1: swap input-channel halves (zr convs: ref concat [x,h] -> cat [h,xt]).
__global__ __launch_bounds__(256) void prep_w(
    const float* __restrict__ w, f16* __restrict__ wt,
    int OC, int IC, int KK, int perm)
{
    int i = blockIdx.x * 256 + threadIdx.x;
    int total = OC * IC * KK;
    if (i >= total) return;
    int oc = i / (IC * KK);
    int r  = i - oc * (IC * KK);
    int ic = r / KK;
    int tap = r - ic * KK;
    int icn = perm ? ((ic < IC / 2) ? ic + IC / 2 : ic - IC / 2) : ic;
    int OCB = OC >> 4, KPT = IC >> 5;
    int ob = oc >> 4, ol = oc & 15;
    int kb = icn >> 5, kg = (icn >> 3) & 3, ch = icn & 7;
    size_t o = (((size_t)tap * OCB + ob) * KPT + kb) * 512 + kg * 128 + ol * 8 + ch;
    wt[o] = (f16)w[i];
}

// blocked cat hi/lo h-region -> fp32 NCHW
__global__ __launch_bounds__(256) void cat_to_nchw(
    const f16* __restrict__ hi, const f16* __restrict__ lo,
    float* __restrict__ dst, int C, int HW, int wsh, int WP, int PIXP, int CB)
{
    int i = blockIdx.x * 256 + threadIdx.x;
    int b = i / (C * HW);
    int r = i - b * (C * HW);
    int c = r / HW;
    int p = r - c * HW;
    int y = p >> wsh, x = p & ((1 << wsh) - 1);
    size_t s = ((size_t)(b * CB + (c >> 5)) * PIXP + (size_t)(y + 2) * WP + (x + 2)) * 32 + (c & 31);
    dst[i] = (float)hi[s] + (float)lo[s] * (1.0f / 4096.0f);
}

// ---------------------------------------------------------------------------
extern "C" void kernel_launch(void* const* d_in, const int* in_sizes, int n_in,
                              void* d_out, int out_size, void* d_ws, size_t ws_size,
                              hipStream_t stream)
{
    (void)in_sizes; (void)n_in; (void)out_size; (void)ws_size;

    const float* input  = (const float*)d_in[0];
    const float* c1_w   = (const float*)d_in[1];
    const float* c1_b   = (const float*)d_in[2];
    const float* g1zr_w = (const float*)d_in[3];
    const float* g1zr_b = (const float*)d_in[4];
    const float* g1h_w  = (const float*)d_in[5];
    const float* g1h_b  = (const float*)d_in[6];
    const float* c2_w   = (const float*)d_in[7];
    const float* c2_b   = (const float*)d_in[8];
    const float* g2zr_w = (const float*)d_in[9];
    const float* g2zr_b = (const float*)d_in[10];
    const float* g2h_w  = (const float*)d_in[11];
    const float* g2h_b  = (const float*)d_in[12];
    const float* c3_w   = (const float*)d_in[13];
    const float* c3_b   = (const float*)d_in[14];
    const float* g3zr_w = (const float*)d_in[15];
    const float* g3zr_b = (const float*)d_in[16];
    const float* g3h_w  = (const float*)d_in[17];
    const float* g3h_b  = (const float*)d_in[18];

    float* out1 = (float*)d_out;                 // [8,64,64,64]  NCHW
    float* out2 = (float*)d_out + 2097152;       // [8,128,32,32]
    float* out3 = (float*)d_out + 3145728;       // [8,128,16,16]

    char* ws = (char*)d_ws;
    size_t off = 0;
    auto takeB = [&](size_t bytes) { char* p = ws + off; off += (bytes + 255) & ~(size_t)255; return p; };

    const size_t WSLACK = 400000;
    f16* wt_g1zr = (f16*)takeB((size_t)25 * 128 * 128 * 2 + WSLACK);
    f16* wt_g1h  = (f16*)takeB((size_t)25 * 64 * 128 * 2 + WSLACK);
    f16* wt_c2   = (f16*)takeB((size_t)16 * 128 * 64 * 2 + WSLACK);
    f16* wt_g2zr = (f16*)takeB((size_t)25 * 256 * 256 * 2 + WSLACK);
    f16* wt_g2h  = (f16*)takeB((size_t)25 * 128 * 256 * 2 + WSLACK);
    f16* wt_c3   = (f16*)takeB((size_t)16 * 128 * 128 * 2 + WSLACK);
    f16* wt_g3zr = (f16*)takeB((size_t)25 * 256 * 256 * 2 + WSLACK);
    f16* wt_g3h  = (f16*)takeB((size_t)25 * 128 * 256 * 2 + WSLACK);

    // blocked padded cat buffers: [b][cblk][pixP][32], hi/lo planes
    const size_t cat1_n = (size_t)8 * 6 * 4624 * 32;   // 68x68, 192ch
    const size_t cat2_n = (size_t)8 * 12 * 1296 * 32;  // 36x36, 384ch
    const size_t cat3_n = (size_t)8 * 12 * 400 * 32;   // 20x20, 384ch
    const size_t ASLACK = 1 << 20;
    f16* cat1h = (f16*)takeB(cat1_n * 2 + ASLACK);
    f16* cat1l = (f16*)takeB(cat1_n * 2 + ASLACK);
    f16* cat2h = (f16*)takeB(cat2_n * 2 + ASLACK);
    f16* cat2l = (f16*)takeB(cat2_n * 2 + ASLACK);
    f16* cat3h = (f16*)takeB(cat3_n * 2 + ASLACK);
    f16* cat3l = (f16*)takeB(cat3_n * 2 + ASLACK);
    float* z1 = (float*)takeB((size_t)8 * 4096 * 64 * 4);
    float* z2 = (float*)takeB((size_t)8 * 1024 * 128 * 4);
    float* z3 = (float*)takeB((size_t)8 * 256 * 128 * 4);

    hipMemsetAsync(cat1h, 0, cat1_n * 2, stream);
    hipMemsetAsync(cat1l, 0, cat1_n * 2, stream);
    hipMemsetAsync(cat2h, 0, cat2_n * 2, stream);
    hipMemsetAsync(cat2l, 0, cat2_n * 2, stream);
    hipMemsetAsync(cat3h, 0, cat3_n * 2, stream);
    hipMemsetAsync(cat3l, 0, cat3_n * 2, stream);

    auto prep = [&](const float* w, f16* wt, int OC, int IC, int KK, int perm) {
        int total = OC * IC * KK;
        prep_w<<<(total + 255) / 256, 256, 0, stream>>>(w, wt, OC, IC, KK, perm);
    };
    prep(g1zr_w, wt_g1zr, 128, 128, 25, 1);
    prep(g1h_w,  wt_g1h,  64, 128, 25, 0);
    prep(c2_w,   wt_c2,   128, 64, 16, 0);
    prep(g2zr_w, wt_g2zr, 256, 256, 25, 1);
    prep(g2h_w,  wt_g2h,  128, 256, 25, 0);
    prep(c3_w,   wt_c3,   128, 128, 16, 0);
    prep(g3zr_w, wt_g3zr, 256, 256, 25, 1);
    prep(g3h_w,  wt_g3h,  128, 256, 25, 0);

    // Software-pipelined wavefront: iteration i runs stage1@t=i, stage2@t=i-1,
    // stage3@t=i-2.  12 steps -> 14 iterations (2 fill, 2 drain).
    for (int i = 0; i < 14; ++i) {
        const int t1 = (i < 12) ? i : -1;
        const int a1 = (i < 12) ? 1 : 0;
        const int a2 = (i >= 1 && i <= 12) ? 1 : 0;
        const int a3 = (i >= 2) ? 1 : 0;

        fused_L1<<<704, 256, 0, stream>>>(
            input, c1_w, c1_b, cat1h, cat1l,
            wt_c2, c2_b, cat2h, cat2l,
            wt_c3, c3_b, cat3h, cat3l,
            t1, a2, a3);
        fused_L2<<<896, 256, 0, stream>>>(
            cat1h, cat1l, wt_g1zr, g1zr_b, z1,
            cat2h, cat2l, wt_g2zr, g2zr_b, z2,
            cat3h, cat3l, wt_g3zr, g3zr_b, z3,
            a1, a2, a3);
        fused_L3<<<704, 256, 0, stream>>>(
            cat1h, cat1l, wt_g1h, g1h_b, z1,
            cat2h, cat2l, wt_g2h, g2h_b, z2,
            cat3h, cat3l, wt_g3h, g3h_b, z3,
            a1, a2, a3);
    }

    cat_to_nchw<<<8192, 256, 0, stream>>>(cat1h, cat1l, out1, 64, 4096, 6, 68, 4624, 6);
    cat_to_nchw<<<4096, 256, 0, stream>>>(cat2h, cat2l, out2, 128, 1024, 5, 36, 1296, 12);
    cat_to_nchw<<<1024, 256, 0, stream>>>(cat3h, cat3l, out3, 128, 256, 4, 20, 400, 12);
}

// Round 13
// 3349.538 us; speedup vs baseline: 1.0402x; 1.0402x over previous
//
#include <hip/hip_runtime.h>
#include <math.h>

typedef _Float16 f16;
typedef __attribute__((ext_vector_type(8))) _Float16 half8;
typedef __attribute__((ext_vector_type(4))) float f32x4;

template <int N> struct ic { static constexpr int v = N; };

static __device__ __forceinline__ float sigmoid_f(float x) { return 1.0f / (1.0f + expf(-x)); }

// exact split: x == (float)hi + (float)lo / 4096 (lo pre-scaled to dodge denormals)
static __device__ __forceinline__ void splitf(float x, f16& hi, f16& lo) {
    hi = (f16)x;
    float r = x - (float)hi;
    lo = (f16)(r * 4096.0f);
}

// vmcnt-only s_waitcnt immediate (gfx9 encoding): vm[3:0] | exp[6:4]=7 | lgkm[11:8]=15 | vm[5:4]@[15:14]
constexpr unsigned vmcnt_enc(int n) {
    return (unsigned)((n & 15) | (7 << 4) | (15 << 8) | ((n >> 4) << 14));
}

// async global->LDS, 16B per lane: LDS dest = uniform base + lane*16, global src per-lane.
static __device__ __forceinline__ void lds_stage16(const f16* src, f16* dst) {
    typedef const __attribute__((address_space(1))) unsigned int* gup;
    typedef __attribute__((address_space(3))) unsigned int* lup;
    __builtin_amdgcn_global_load_lds((gup)(const void*)src, (lup)(void*)dst, 16, 0, 0);
}

// ---------------------------------------------------------------------------
// Tap-decomposed implicit-GEMM conv, f16 MFMA, 2-term activation split,
// fp32 accumulate.
// R13 = R10 verbatim (empirical optimum of this structure, 3452us).
// FINAL LEDGER of the design space:
//   - oc-tile width: NOC=8 where OC allows (R9/R10: A-redundancy cut + 16
//     MFMA/wait-slot, fused_L2 180->151); NOC halving regresses (R5).
//   - per-wave tile ceiling: NG*NOC=8 fragments (128 acc VGPRs) is the
//     register budget; NG=2+NOC=8 would need 128 more.
//   - B read-ahead BAH=1 optimal (R6 isolated deeper BAH as regression).
//   - Pipeline depth D: compiler collapses software pipelines at IR level
//     (R3 VGPR=80 evidence); forcing via sched_barrier regresses (R4).
//   - Barrier placement: group-end counted-vmcnt optimal; early-barrier +
//     cross-preload REFUTED (R12: exposes last-step lgkm drain, +16 VGPR,
//     fused_L2 151->158).
//   - Occupancy: not the limiter (R5: 54% occ ran SLOWER).
//   - RACE FIX (R9, verified R10): sched_barrier(0) after stage_lds pins
//     vm-issue order [stage pieces][A-loads] that the counted vmcnt assumes;
//     without it A-loads hoist above the stage and the wait can leave a
//     stage piece in flight past the barrier (R8 state3 corruption).
//   - LPT block ordering in fused launchers (R4: -290us on L1/L3).
// Remaining gap (MfmaUtil 35%, HBM 11%): per-slot issue latency; source-
// level scheduling cannot remove it (R4/R11/R12) -- would need inline-asm
// K-loop (AITER-style).
//   A-frag: lane&15=pixel, k=(lane>>4)*8+j ; B-frag: lane&15=oc, same k.
//   D-frag: col(oc)=lane&15, row(pixel)=(lane>>4)*4+reg  [HW-verified]
// ---------------------------------------------------------------------------
template <int KH, int KW, int KPT, int MODE, int NG, int NOC, int D, int STG, int BAH,
          int CBI, int KB0, int WPI, int PIXPI,
          int WSH, int HWOUT, int OC, int STRIDE, int POFF,
          int CBO, int OCH0, int WPO, int PIXPO>
static __device__ __forceinline__ void gemm_conv_body(
    int bx, int by, int b,
    const f16* Ah, const f16* Al, const f16* __restrict__ Wt,
    const float* __restrict__ bias, const float* __restrict__ zbuf,
    float* zout, f16* Oh, f16* Ol, f16* smem)
{
    constexpr int NSTEP = KH * KW * KPT;
    constexpr int WOUT  = 1 << WSH;
    constexpr int OCB   = OC / 16;
    constexpr int NGRP  = NSTEP / STG;
    constexpr int U     = (D > STG) ? (D / STG) : 1;   // phase-unroll factor
    constexpr int NB    = BAH + 1;                     // B ring depth
    constexpr int PPW   = (STG * NOC) / 4;             // staged 1KB pieces per wave
    static_assert(NSTEP % STG == 0, "NSTEP % STG");
    static_assert(NSTEP % D == 0, "NSTEP % D");
    static_assert(U == 1 ? (STG % D == 0) : (D % STG == 0 && NGRP % U == 0), "phase");
    static_assert(U <= 2, "U support");
    static_assert(BAH >= 1 && BAH < STG, "BAH range");
    static_assert(STG * NOC * 512 <= 8192, "group fits buffer");

    const int lane = threadIdx.x & 63;
    const int wave = threadIdx.x >> 6;
    const int pixbase = (bx * 4 + wave) * (NG * 16);
    const int ocbase  = by * (NOC * 16);

    const f16* ph[NG];
    const f16* pl[NG];
#pragma unroll
    for (int g = 0; g < NG; ++g) {
        int apix = pixbase + 16 * g + (lane & 15);
        int y = apix >> WSH, x = apix & (WOUT - 1);
        int p0 = (y * STRIDE + POFF) * WPI + (x * STRIDE + POFF);
        size_t o = ((size_t)(b * CBI + KB0) * PIXPI + p0) * 32 + (lane >> 4) * 8;
        ph[g] = Ah + o;
        pl[g] = Al + o;
    }

    int lk = 0, lkx = 0;
    auto advance = [&]() {
#pragma unroll
        for (int g = 0; g < NG; ++g) { ph[g] += (size_t)PIXPI * 32; pl[g] += (size_t)PIXPI * 32; }
        if (++lk == KPT) {
            lk = 0;
            int shift = 1;
            if (++lkx == KW) { lkx = 0; shift = WPI - (KW - 1); }
            const long ad = (long)shift * 32 - (long)KPT * PIXPI * 32;
#pragma unroll
            for (int g = 0; g < NG; ++g) { ph[g] += ad; pl[g] += ad; }
        }
    };

    // B piece (1KB = 512 f16 = [kgrp4][oc16][ch8]) for flat step s, oc-block j
    auto bpiece = [&](int s, int j) -> const f16* {
        int t = s / KPT, kb = s % KPT;
        return Wt + (((size_t)(t * OCB + by * NOC + j)) * KPT + kb) * 512;
    };

    auto stage_lds = [&](int g0, f16* dst) {
#pragma unroll
        for (int p = 0; p < PPW; ++p) {
            const int pc = wave * PPW + p;
            const int kk = pc / NOC, j = pc % NOC;
            lds_stage16(bpiece(g0 * STG + kk, j) + lane * 8, dst + pc * 512);
        }
    };

    half8 bh[D][NG], bl[D][NG];
    half8 bwreg[NB][NOC];
    f32x4 acc[NG][NOC] = {};
    f32x4 acc2[NG][NOC] = {};

    // prologue: stage group 0; fill A pipeline D-1 deep; certify B via counted vmcnt.
    // sched_barrier pins stage issue BEFORE the A prologue loads (count assumption).
    stage_lds(0, smem);
    __builtin_amdgcn_sched_barrier(0);
#pragma unroll
    for (int s = 0; s < D - 1; ++s) {
#pragma unroll
        for (int g = 0; g < NG; ++g) {
            bh[s][g] = *(const half8*)ph[g];
            bl[s][g] = *(const half8*)pl[g];
        }
        advance();
    }
    __builtin_amdgcn_s_waitcnt(vmcnt_enc((D - 1) * NG * 2));
    asm volatile("" ::: "memory");
    __builtin_amdgcn_s_barrier();
    __builtin_amdgcn_sched_barrier(0);

    auto group_body = [&](auto phc, int gi) __attribute__((always_inline)) {
        constexpr int PH = decltype(phc)::v;
        constexpr int PB = PH * STG;                 // flat-step phase base (mod D)
        const int par = (U == 2) ? PH : (gi & 1);
        f16* cur = smem + par * 8192;
        f16* nxt = smem + (par ^ 1) * 8192;
        if (gi + 1 < NGRP) {
            stage_lds(gi + 1, nxt);                  // async into other buffer
            __builtin_amdgcn_sched_barrier(0);       // pin: stage issues before group's A-loads
        }
#pragma unroll
        for (int q = 0; q < BAH; ++q)
#pragma unroll
            for (int j = 0; j < NOC; ++j)
                bwreg[q % NB][j] = *(const half8*)(cur + (q * NOC + j) * 512 + lane * 8);
#pragma unroll
        for (int kk = 0; kk < STG; ++kk) {
            if (kk + BAH < STG) {
#pragma unroll
                for (int j = 0; j < NOC; ++j)
                    bwreg[(kk + BAH) % NB][j] = *(const half8*)(cur + ((kk + BAH) * NOC + j) * 512 + lane * 8);
            }
            const int ls = (PB + kk + D - 1) % D;    // compile-time after unroll
#pragma unroll
            for (int g = 0; g < NG; ++g) {
                bh[ls][g] = *(const half8*)ph[g];
                bl[ls][g] = *(const half8*)pl[g];
            }
            advance();
            const int dd = (PB + kk) % D;
            __builtin_amdgcn_s_setprio(1);
#pragma unroll
            for (int j = 0; j < NOC; ++j)
#pragma unroll
                for (int g = 0; g < NG; ++g) {
                    acc[g][j]  = __builtin_amdgcn_mfma_f32_16x16x32_f16(bh[dd][g], bwreg[kk % NB][j], acc[g][j], 0, 0, 0);
                    acc2[g][j] = __builtin_amdgcn_mfma_f32_16x16x32_f16(bl[dd][g], bwreg[kk % NB][j], acc2[g][j], 0, 0, 0);
                }
            __builtin_amdgcn_s_setprio(0);
        }
        if (gi + 1 < NGRP) {
            // certify own B-stage done (oldest); this group's STG*NG*2 A-loads stay in flight
            __builtin_amdgcn_s_waitcnt(vmcnt_enc(STG * NG * 2));
            asm volatile("" ::: "memory");
            __builtin_amdgcn_s_barrier();
            __builtin_amdgcn_sched_barrier(0);
        }
    };

#pragma unroll 1
    for (int gi0 = 0; gi0 < NGRP; gi0 += U) {
        group_body(ic<0>{}, gi0);
        if constexpr (U == 2) group_body(ic<1>{}, gi0 + 1);
    }

    constexpr int Cc = (MODE == 0) ? (OC >> 1) : OC;
#pragma unroll
    for (int g = 0; g < NG; ++g) {
#pragma unroll
        for (int j = 0; j < NOC; ++j) {
            const int oc = ocbase + j * 16 + (lane & 15);
            const float bv = bias[oc];
#pragma unroll
            for (int r = 0; r < 4; ++r) {
                const int pix = pixbase + 16 * g + ((lane >> 4) << 2) + r;
                const int y = pix >> WSH, x = pix & (WOUT - 1);
                const int pr = (y + 2) * WPI + (x + 2);
                const int pwr = (y + 2) * WPO + (x + 2);
                const size_t pz = (size_t)b * HWOUT + pix;
                float a = acc[g][j][r] + acc2[g][j][r] * (1.0f / 4096.0f) + bv;
                if (MODE == 0) {
                    float s = sigmoid_f(a);
                    if (oc < Cc) {
                        zout[pz * Cc + oc] = s;
                    } else {
                        int hch = oc - Cc;
                        size_t hidx = ((size_t)(b * CBI + (hch >> 5)) * PIXPI + pr) * 32 + (hch & 31);
                        float hv = (float)Ah[hidx] + (float)Al[hidx] * (1.0f / 4096.0f);
                        float rh = s * hv;
                        f16 hi, lo; splitf(rh, hi, lo);
                        int wch = Cc + oc;  // = 2C + (oc-C)
                        size_t widx = ((size_t)(b * CBO + (wch >> 5)) * PIXPO + pwr) * 32 + (wch & 31);
                        Oh[widx] = hi; Ol[widx] = lo;
                    }
                } else if (MODE == 1) {
                    size_t hidx = ((size_t)(b * CBI + (oc >> 5)) * PIXPI + pr) * 32 + (oc & 31);
                    float hv = (float)Ah[hidx] + (float)Al[hidx] * (1.0f / 4096.0f);
                    float zv = zbuf[pz * Cc + oc];
                    float hn = (1.f - zv) * hv + zv * tanhf(a);
                    f16 hi, lo; splitf(hn, hi, lo);
                    Oh[hidx] = hi; Ol[hidx] = lo;
                } else {
                    f16 hi, lo; splitf(a, hi, lo);
                    int wch = OCH0 + oc;
                    size_t widx = ((size_t)(b * CBO + (wch >> 5)) * PIXPO + pwr) * 32 + (wch & 31);
                    Oh[widx] = hi; Ol[widx] = lo;
                }
            }
        }
    }
}

// ---------------------------------------------------------------------------
// conv1 body: IC=1, k4 s2 p1, 128x128 -> 64x64, OC=64, fp32 direct; writes f16
// hi/lo into blocked cat1 xt region (ch [64,128), cblk 2..3, halo 2).
// ---------------------------------------------------------------------------
static __device__ __forceinline__ void conv1_body(
    int bx, int b,
    const float* __restrict__ in, const float* __restrict__ w,
    const float* __restrict__ bias, f16* Oh, f16* Ol)
{
    const int tid = threadIdx.x;
    const int px  = bx * 64 + (tid & 63);
    const int ocg = tid >> 6;
    const int y = px >> 6, x = px & 63;
    const float* src = in + (size_t)b * 196608;
    float v[16];
#pragma unroll
    for (int ky = 0; ky < 4; ++ky)
#pragma unroll
        for (int kx = 0; kx < 4; ++kx) {
            int iy = 2 * y - 1 + ky, ix = 2 * x - 1 + kx;
            v[ky * 4 + kx] = ((unsigned)iy < 128u && (unsigned)ix < 128u) ? src[iy * 128 + ix] : 0.f;
        }
    const int p = (y + 2) * 68 + (x + 2);
#pragma unroll
    for (int o = 0; o < 16; ++o) {
        int ch = 64 + ocg * 16 + o;
        float s = bias[ch - 64];
        const float* wr = w + (ch - 64) * 16;
#pragma unroll
        for (int t = 0; t < 16; ++t) s += wr[t] * v[t];
        f16 hi, lo; splitf(s, hi, lo);
        size_t idx = ((size_t)(b * 6 + (ch >> 5)) * 4624 + p) * 32 + (ch & 31);
        Oh[idx] = hi; Ol[idx] = lo;
    }
}

// ---------------------------------------------------------------------------
// Horizontally-fused pipeline phases.  GRU wavefront: stage1@t, stage2@t-1,
// stage3@t-2 are independent -> fuse each sub-phase across stages.
// LPT ordering: longest-per-block branch gets the LOWEST block IDs.
// ---------------------------------------------------------------------------

// L1: c3(t-2) NOC=4 [0,64) | c2(t-1) NOC=8 [64,192) | conv1(t) [192,704)
__global__ __launch_bounds__(256) void fused_L1(
    const float* __restrict__ input, const float* __restrict__ c1w, const float* __restrict__ c1b,
    f16* cat1h, f16* cat1l,
    const f16* __restrict__ wt_c2, const float* __restrict__ c2b, f16* cat2h, f16* cat2l,
    const f16* __restrict__ wt_c3, const float* __restrict__ c3b, f16* cat3h, f16* cat3l,
    int t1, int a2, int a3)
{
    __shared__ f16 smem[2 * 8192];
    const int lin = blockIdx.x;
    if (lin < 64) {
        if (!a3) return;
        gemm_conv_body<4, 4, 4, 2, 1, 4, 8, 4, 1, 12, 0, 36, 1296, 4, 256, 128, 2, 1, 12, 128, 20, 400>(
            lin & 3, (lin >> 2) & 1, lin >> 3,
            cat2h, cat2l, wt_c3, c3b, nullptr, nullptr, cat3h, cat3l, smem);
    } else if (lin < 192) {
        if (!a2) return;
        const int l = lin - 64;
        gemm_conv_body<4, 4, 2, 2, 1, 8, 4, 2, 1, 6, 0, 68, 4624, 5, 1024, 128, 2, 1, 12, 128, 36, 1296>(
            l & 15, 0, l >> 4,
            cat1h, cat1l, wt_c2, c2b, nullptr, nullptr, cat2h, cat2l, smem);
    } else {
        if (t1 < 0) return;
        const int l = lin - 192;
        conv1_body(l & 63, l >> 6, input + (size_t)t1 * 16384, c1w, c1b, cat1h, cat1l);
    }
}

// L2: g2zr(t-1) NOC=8 [0,256) | g3zr(t-2) NOC=4 [256,384) | g1zr(t) NOC=8 [384,896)
__global__ __launch_bounds__(256) void fused_L2(
    f16* cat1h, f16* cat1l, const f16* __restrict__ wt_g1zr, const float* __restrict__ g1zrb, float* z1,
    f16* cat2h, f16* cat2l, const f16* __restrict__ wt_g2zr, const float* __restrict__ g2zrb, float* z2,
    f16* cat3h, f16* cat3l, const f16* __restrict__ wt_g3zr, const float* __restrict__ g3zrb, float* z3,
    int a1, int a2, int a3)
{
    __shared__ f16 smem[2 * 8192];
    const int lin = blockIdx.x;
    if (lin < 256) {
        if (!a2) return;
        // g2zr: OC=256, NOC=8 -> by in {0,1}; A redundancy 4x->2x; 16 MFMA/step
        gemm_conv_body<5, 5, 8, 0, 1, 8, 4, 2, 1, 12, 0, 36, 1296, 5, 1024, 256, 1, 0, 12, 0, 36, 1296>(
            lin & 15, (lin >> 4) & 1, lin >> 5,
            cat2h, cat2l, wt_g2zr, g2zrb, nullptr, z2, cat2h, cat2l, smem);
    } else if (lin < 384) {
        if (!a3) return;
        const int l = lin - 256;
        // g3zr: NOC=4 (wide config under the R9 race fix -- verified R10)
        gemm_conv_body<5, 5, 8, 0, 1, 4, 8, 4, 1, 12, 0, 20, 400, 4, 256, 256, 1, 0, 12, 0, 20, 400>(
            l & 3, (l >> 2) & 3, l >> 4,
            cat3h, cat3l, wt_g3zr, g3zrb, nullptr, z3, cat3h, cat3l, smem);
    } else {
        if (!a1) return;
        const int l = lin - 384;
        // g1zr: OC=128, NOC=8 -> by=0; A redundancy 2x->1x
        gemm_conv_body<5, 5, 4, 0, 1, 8, 4, 2, 1, 6, 0, 68, 4624, 6, 4096, 128, 1, 0, 6, 0, 68, 4624>(
            l & 63, 0, l >> 6,
            cat1h, cat1l, wt_g1zr, g1zrb, nullptr, z1, cat1h, cat1l, smem);
    }
}

// L3: g2h(t-1) NOC=8 [0,128) | g3h(t-2) NOC=4 [128,192) | g1h(t) NOC=4 [192,704)
__global__ __launch_bounds__(256) void fused_L3(
    f16* cat1h, f16* cat1l, const f16* __restrict__ wt_g1h, const float* __restrict__ g1hb, const float* z1,
    f16* cat2h, f16* cat2l, const f16* __restrict__ wt_g2h, const float* __restrict__ g2hb, const float* z2,
    f16* cat3h, f16* cat3l, const f16* __restrict__ wt_g3h, const float* __restrict__ g3hb, const float* z3,
    int a1, int a2, int a3)
{
    __shared__ f16 smem[2 * 8192];
    const int lin = blockIdx.x;
    if (lin < 128) {
        if (!a2) return;
        // g2h: OC=128, NOC=8 -> by=0; A redundancy 2x->1x; 16 MFMA/step
        gemm_conv_body<5, 5, 8, 1, 1, 8, 4, 2, 1, 12, 4, 36, 1296, 5, 1024, 128, 1, 0, 12, 0, 36, 1296>(
            lin & 15, 0, lin >> 4,
            cat2h, cat2l, wt_g2h, g2hb, z2, nullptr, cat2h, cat2l, smem);
    } else if (lin < 192) {
        if (!a3) return;
        const int l = lin - 128;
        // g3h: OC=128, NOC=4 -> by in {0,1}
        gemm_conv_body<5, 5, 8, 1, 1, 4, 8, 4, 1, 12, 4, 20, 400, 4, 256, 128, 1, 0, 12, 0, 20, 400>(
            l & 3, (l >> 2) & 1, l >> 3,
            cat3h, cat3l, wt_g3h, g3hb, z3, nullptr, cat3h, cat3l, smem);
    } else {
        if (!a1) return;
        const int l = lin - 192;
        gemm_conv_body<5, 5, 4, 1, 1, 4, 4, 4, 2, 6, 2, 68, 4624, 6, 4096, 64, 1, 0, 6, 0, 68, 4624>(
            l & 63, 0, l >> 6,
            cat1h, cat1l, wt_g1h, g1hb, z1, nullptr, cat1h, cat1l, smem);
    }
}

// w[oc][ic][kh][kw] fp32 -> blocked f16 [tap][ocblk][kblk][kgrp4][oc16][ch8].
// perm=1: swap input-channel halves (zr convs: ref concat [x,h] -> cat [h,xt]).
__global__ __launch_bounds__(256) void prep_w(
    const float* __restrict__ w, f16* __restrict__ wt,
    int OC, int IC, int KK, int perm)
{
    int i = blockIdx.x * 256 + threadIdx.x;
    int total = OC * IC * KK;
    if (i >= total) return;
    int oc = i / (IC * KK);
    int r  = i - oc * (IC * KK);
    int ic = r / KK;
    int tap = r - ic * KK;
    int icn = perm ? ((ic < IC / 2) ? ic + IC / 2 : ic - IC / 2) : ic;
    int OCB = OC >> 4, KPT = IC >> 5;
    int ob = oc >> 4, ol = oc & 15;
    int kb = icn >> 5, kg = (icn >> 3) & 3, ch = icn & 7;
    size_t o = (((size_t)tap * OCB + ob) * KPT + kb) * 512 + kg * 128 + ol * 8 + ch;
    wt[o] = (f16)w[i];
}

// blocked cat hi/lo h-region -> fp32 NCHW
__global__ __launch_bounds__(256) void cat_to_nchw(
    const f16* __restrict__ hi, const f16* __restrict__ lo,
    float* __restrict__ dst, int C, int HW, int wsh, int WP, int PIXP, int CB)
{
    int i = blockIdx.x * 256 + threadIdx.x;
    int b = i / (C * HW);
    int r = i - b * (C * HW);
    int c = r / HW;
    int p = r - c * HW;
    int y = p >> wsh, x = p & ((1 << wsh) - 1);
    size_t s = ((size_t)(b * CB + (c >> 5)) * PIXP + (size_t)(y + 2) * WP + (x + 2)) * 32 + (c & 31);
    dst[i] = (float)hi[s] + (float)lo[s] * (1.0f / 4096.0f);
}

// ---------------------------------------------------------------------------
extern "C" void kernel_launch(void* const* d_in, const int* in_sizes, int n_in,
                              void* d_out, int out_size, void* d_ws, size_t ws_size,
                              hipStream_t stream)
{
    (void)in_sizes; (void)n_in; (void)out_size; (void)ws_size;

    const float* input  = (const float*)d_in[0];
    const float* c1_w   = (const float*)d_in[1];
    const float* c1_b   = (const float*)d_in[2];
    const float* g1zr_w = (const float*)d_in[3];
    const float* g1zr_b = (const float*)d_in[4];
    const float* g1h_w  = (const float*)d_in[5];
    const float* g1h_b  = (const float*)d_in[6];
    const float* c2_w   = (const float*)d_in[7];
    const float* c2_b   = (const float*)d_in[8];
    const float* g2zr_w = (const float*)d_in[9];
    const float* g2zr_b = (const float*)d_in[10];
    const float* g2h_w  = (const float*)d_in[11];
    const float* g2h_b  = (const float*)d_in[12];
    const float* c3_w   = (const float*)d_in[13];
    const float* c3_b   = (const float*)d_in[14];
    const float* g3zr_w = (const float*)d_in[15];
    const float* g3zr_b = (const float*)d_in[16];
    const float* g3h_w  = (const float*)d_in[17];
    const float* g3h_b  = (const float*)d_in[18];

    float* out1 = (float*)d_out;                 // [8,64,64,64]  NCHW
    float* out2 = (float*)d_out + 2097152;       // [8,128,32,32]
    float* out3 = (float*)d_out + 3145728;       // [8,128,16,16]

    char* ws = (char*)d_ws;
    size_t off = 0;
    auto takeB = [&](size_t bytes) { char* p = ws + off; off += (bytes + 255) & ~(size_t)255; return p; };

    const size_t WSLACK = 400000;
    f16* wt_g1zr = (f16*)takeB((size_t)25 * 128 * 128 * 2 + WSLACK);
    f16* wt_g1h  = (f16*)takeB((size_t)25 * 64 * 128 * 2 + WSLACK);
    f16* wt_c2   = (f16*)takeB((size_t)16 * 128 * 64 * 2 + WSLACK);
    f16* wt_g2zr = (f16*)takeB((size_t)25 * 256 * 256 * 2 + WSLACK);
    f16* wt_g2h  = (f16*)takeB((size_t)25 * 128 * 256 * 2 + WSLACK);
    f16* wt_c3   = (f16*)takeB((size_t)16 * 128 * 128 * 2 + WSLACK);
    f16* wt_g3zr = (f16*)takeB((size_t)25 * 256 * 256 * 2 + WSLACK);
    f16* wt_g3h  = (f16*)takeB((size_t)25 * 128 * 256 * 2 + WSLACK);

    // blocked padded cat buffers: [b][cblk][pixP][32], hi/lo planes
    const size_t cat1_n = (size_t)8 * 6 * 4624 * 32;   // 68x68, 192ch
    const size_t cat2_n = (size_t)8 * 12 * 1296 * 32;  // 36x36, 384ch
    const size_t cat3_n = (size_t)8 * 12 * 400 * 32;   // 20x20, 384ch
    const size_t ASLACK = 1 << 20;
    f16* cat1h = (f16*)takeB(cat1_n * 2 + ASLACK);
    f16* cat1l = (f16*)takeB(cat1_n * 2 + ASLACK);
    f16* cat2h = (f16*)takeB(cat2_n * 2 + ASLACK);
    f16* cat2l = (f16*)takeB(cat2_n * 2 + ASLACK);
    f16* cat3h = (f16*)takeB(cat3_n * 2 + ASLACK);
    f16* cat3l = (f16*)takeB(cat3_n * 2 + ASLACK);
    float* z1 = (float*)takeB((size_t)8 * 4096 * 64 * 4);
    float* z2 = (float*)takeB((size_t)8 * 1024 * 128 * 4);
    float* z3 = (float*)takeB((size_t)8 * 256 * 128 * 4);

    hipMemsetAsync(cat1h, 0, cat1_n * 2, stream);
    hipMemsetAsync(cat1l, 0, cat1_n * 2, stream);
    hipMemsetAsync(cat2h, 0, cat2_n * 2, stream);
    hipMemsetAsync(cat2l, 0, cat2_n * 2, stream);
    hipMemsetAsync(cat3h, 0, cat3_n * 2, stream);
    hipMemsetAsync(cat3l, 0, cat3_n * 2, stream);

    auto prep = [&](const float* w, f16* wt, int OC, int IC, int KK, int perm) {
        int total = OC * IC * KK;
        prep_w<<<(total + 255) / 256, 256, 0, stream>>>(w, wt, OC, IC, KK, perm);
    };
    prep(g1zr_w, wt_g1zr, 128, 128, 25, 1);
    prep(g1h_w,  wt_g1h,  64, 128, 25, 0);
    prep(c2_w,   wt_c2,   128, 64, 16, 0);
    prep(g2zr_w, wt_g2zr, 256, 256, 25, 1);
    prep(g2h_w,  wt_g2h,  128, 256, 25, 0);
    prep(c3_w,   wt_c3,   128, 128, 16, 0);
    prep(g3zr_w, wt_g3zr, 256, 256, 25, 1);
    prep(g3h_w,  wt_g3h,  128, 256, 25, 0);

    // Software-pipelined wavefront: iteration i runs stage1@t=i, stage2@t=i-1,
    // stage3@t=i-2.  12 steps -> 14 iterations (2 fill, 2 drain).
    for (int i = 0; i < 14; ++i) {
        const int t1 = (i < 12) ? i : -1;
        const int a1 = (i < 12) ? 1 : 0;
        const int a2 = (i >= 1 && i <= 12) ? 1 : 0;
        const int a3 = (i >= 2) ? 1 : 0;

        fused_L1<<<704, 256, 0, stream>>>(
            input, c1_w, c1_b, cat1h, cat1l,
            wt_c2, c2_b, cat2h, cat2l,
            wt_c3, c3_b, cat3h, cat3l,
            t1, a2, a3);
        fused_L2<<<896, 256, 0, stream>>>(
            cat1h, cat1l, wt_g1zr, g1zr_b, z1,
            cat2h, cat2l, wt_g2zr, g2zr_b, z2,
            cat3h, cat3l, wt_g3zr, g3zr_b, z3,
            a1, a2, a3);
        fused_L3<<<704, 256, 0, stream>>>(
            cat1h, cat1l, wt_g1h, g1h_b, z1,
            cat2h, cat2l, wt_g2h, g2h_b, z2,
            cat3h, cat3l, wt_g3h, g3h_b, z3,
            a1, a2, a3);
    }

    cat_to_nchw<<<8192, 256, 0, stream>>>(cat1h, cat1l, out1, 64, 4096, 6, 68, 4624, 6);
    cat_to_nchw<<<4096, 256, 0, stream>>>(cat2h, cat2l, out2, 128, 1024, 5, 36, 1296, 12);
    cat_to_nchw<<<1024, 256, 0, stream>>>(cat3h, cat3l, out3, 128, 256, 4, 20, 400, 12);
}